// Round 5
// baseline (306.667 us; speedup 1.0000x reference)
//
#include <hip/hip_runtime.h>
#include <hip/hip_fp16.h>
#include <math.h>

#define F_IN   128
#define HEADS  4
#define HID    32
#define NCLS   8
#define SLOPE  0.2f

// ---------------------------------------------------------------------------
// deg zero (harness poisons ws each call)
// ---------------------------------------------------------------------------
__global__ void k_zero(int* __restrict__ deg, int N) {
    int i = blockIdx.x * 256 + threadIdx.x;
    if (i < N) deg[i] = 0;
}

// ---------------------------------------------------------------------------
// Degree count, reading edge_index directly.
// int64-layout detection: odd words of first 128 ints all zero iff int64.
// ---------------------------------------------------------------------------
__global__ void k_count(const int* __restrict__ ei, int* __restrict__ deg, int E) {
    int e = blockIdx.x * 256 + threadIdx.x;
    int probe = ei[2 * (threadIdx.x & 63) + 1];
    bool is64 = (__ballot(probe != 0) == 0ULL);
    if (e >= E) return;
    int d = is64 ? ei[2 * E + 2 * e] : ei[E + e];
    atomicAdd(&deg[d], 1);
}

// ---------------------------------------------------------------------------
// Hierarchical exclusive scan of (deg[i] + 1)  (self loop folded in).
// 1024-elem chunks; single-wave top scan (NB <= 64 -> N <= 65536).
// ---------------------------------------------------------------------------
__global__ void k_scan1(const int* __restrict__ deg, int* __restrict__ offs,
                        int* __restrict__ bsum, int N) {
    __shared__ int wtot[4];
    __shared__ int wbase[4];
    int tid = threadIdx.x;
    int lane = tid & 63, wid = tid >> 6;
    int i0 = blockIdx.x * 1024 + tid * 4;
    int v[4];
    #pragma unroll
    for (int k = 0; k < 4; k++) v[k] = (i0 + k < N) ? deg[i0 + k] + 1 : 0;
    int t = v[0] + v[1] + v[2] + v[3];
    int incl = t;
    #pragma unroll
    for (int off = 1; off < 64; off <<= 1) {
        int u = __shfl_up(incl, off, 64);
        if (lane >= off) incl += u;
    }
    if (lane == 63) wtot[wid] = incl;
    __syncthreads();
    if (tid == 0) {
        int run = 0;
        #pragma unroll
        for (int w = 0; w < 4; w++) { wbase[w] = run; run += wtot[w]; }
        bsum[blockIdx.x] = run;
    }
    __syncthreads();
    int ebase = wbase[wid] + incl - t;
    #pragma unroll
    for (int k = 0; k < 4; k++) {
        if (i0 + k < N) offs[i0 + k] = ebase;
        ebase += v[k];
    }
}

__global__ void k_scan2(int* __restrict__ bsum, int* __restrict__ offs, int NB, int N) {
    int lane = threadIdx.x;           // 64 threads
    int v = (lane < NB) ? bsum[lane] : 0;
    int incl = v;
    #pragma unroll
    for (int off = 1; off < 64; off <<= 1) {
        int u = __shfl_up(incl, off, 64);
        if (lane >= off) incl += u;
    }
    if (lane < NB) bsum[lane] = incl - v;   // exclusive block base
    if (lane == 63) offs[N] = incl;         // grand total = E + N
}

__global__ void k_scan3(const int* __restrict__ bsum, int* __restrict__ offs,
                        int* __restrict__ cur, int N) {
    int add = bsum[blockIdx.x];
    int i0 = blockIdx.x * 1024 + threadIdx.x * 4;
    #pragma unroll
    for (int k = 0; k < 4; k++) {
        int i = i0 + k;
        if (i < N) { int o = offs[i] + add; offs[i] = o; cur[i] = o; }
    }
}

// ---------------------------------------------------------------------------
// CSR fill, reading edge_index directly (self loops appended).
// ---------------------------------------------------------------------------
__global__ void k_fill(const int* __restrict__ ei, int* __restrict__ cur,
                       int* __restrict__ csr, int E, int N) {
    int i = blockIdx.x * 256 + threadIdx.x;
    int probe = ei[2 * (threadIdx.x & 63) + 1];
    bool is64 = (__ballot(probe != 0) == 0ULL);
    if (i >= E + N) return;
    int s, d;
    if (i < E) {
        if (is64) { s = ei[2 * i]; d = ei[2 * E + 2 * i]; }
        else      { s = ei[i];     d = ei[E + i]; }
    } else { s = i - E; d = i - E; }          // self loop
    int pos = atomicAdd(&cur[d], 1);
    csr[pos] = s;
}

// ---------------------------------------------------------------------------
// GEMM1 + fused att1: xw1h[N,128] (fp16) = x @ W1; asrc1/adst1 from fp32 acc.
// 16 rows / block of 256; 32-lane butterfly per row per head.
// ---------------------------------------------------------------------------
__global__ void k_gemm1(const float* __restrict__ x, const float* __restrict__ W,
                        const float* __restrict__ as1, const float* __restrict__ ad1,
                        __half* __restrict__ xwh, float* __restrict__ asrc,
                        float* __restrict__ adst, int N) {
    __shared__ float xs[16][128];
    int r0 = blockIdx.x * 16;
    for (int i = threadIdx.x; i < 16 * 32; i += 256) {   // 512 float4 = whole tile
        int q = i & 31;
        int r = i >> 5;
        int gr = r0 + r;
        float4 v = make_float4(0.f, 0.f, 0.f, 0.f);
        if (gr < N) v = ((const float4*)(x + (size_t)gr * 128))[q];
        ((float4*)xs)[i] = v;
    }
    __syncthreads();
    int c  = threadIdx.x & 127;
    int rg = threadIdx.x >> 7;
    int lane = threadIdx.x & 63;
    float acc[8] = {0.f, 0.f, 0.f, 0.f, 0.f, 0.f, 0.f, 0.f};
    #pragma unroll 8
    for (int k4 = 0; k4 < 32; k4++) {
        float w0 = W[(4 * k4 + 0) * 128 + c];
        float w1 = W[(4 * k4 + 1) * 128 + c];
        float w2 = W[(4 * k4 + 2) * 128 + c];
        float w3 = W[(4 * k4 + 3) * 128 + c];
        #pragma unroll
        for (int i = 0; i < 8; i++) {
            float4 xv = *(const float4*)&xs[rg * 8 + i][4 * k4];
            acc[i] += xv.x * w0 + xv.y * w1 + xv.z * w2 + xv.w * w3;
        }
    }
    float sa = as1[c], da = ad1[c];
    int h = c >> 5;                       // head owned by this 32-lane group
    #pragma unroll
    for (int i = 0; i < 8; i++) {
        int r = r0 + rg * 8 + i;
        if (r < N) xwh[(size_t)r * 128 + c] = __float2half(acc[i]);
        float ps = acc[i] * sa;
        float pd = acc[i] * da;
        #pragma unroll
        for (int mk = 1; mk < 32; mk <<= 1) {
            ps += __shfl_xor(ps, mk);
            pd += __shfl_xor(pd, mk);
        }
        if ((lane & 31) == 0 && r < N) {
            asrc[r * 4 + h] = ps;
            adst[r * 4 + h] = pd;
        }
    }
}

// ---------------------------------------------------------------------------
// Layer-1 aggregation + fused GEMM2/att2 epilogue. One wave per dst node.
// lane -> head h = lane>>4, channels {ch, ch+1}, ch = h*32 + 2*(lane&15).
// Online softmax, 4-edge unroll. Epilogue: W2 columns in REGISTERS (no LDS),
// value-splitting butterfly (10 shuffles) for the 8 xw2 sums.
// ---------------------------------------------------------------------------
__global__ void k_agg1(const __half* __restrict__ xwh, const float* __restrict__ asrc,
                       const float* __restrict__ adst, const int* __restrict__ offs,
                       const int* __restrict__ csr, const float* __restrict__ b1,
                       const float* __restrict__ W2, const float* __restrict__ as2,
                       const float* __restrict__ ad2, float* __restrict__ xw2,
                       float* __restrict__ asrc2, float* __restrict__ adst2, int N) {
    int node = (blockIdx.x * blockDim.x + threadIdx.x) >> 6;
    int lane = threadIdx.x & 63;
    if (node >= N) return;
    int h  = lane >> 4;
    int ch = h * 32 + 2 * (lane & 15);

    // W2 rows ch, ch+1 into registers (L1-resident, 32B-aligned float4s)
    const float4* w2p = (const float4*)(W2 + ch * 8);
    float4 wa0 = w2p[0], wa1 = w2p[1];    // W2[ch][0..8)
    float4 wb0 = w2p[2], wb1 = w2p[3];    // W2[ch+1][0..8)
    float a_s = as2[lane & 7];
    float a_d = ad2[lane & 7];

    float adst_h = adst[node * 4 + h];
    int beg = offs[node], end = offs[node + 1];
    float m = -3.0e38f, s = 0.f, a0 = 0.f, a1 = 0.f;
    int j = beg;
    for (; j + 4 <= end; j += 4) {
        int s0 = csr[j], s1 = csr[j + 1], s2 = csr[j + 2], s3 = csr[j + 3];
        float e0 = asrc[s0 * 4 + h] + adst_h;
        float e1 = asrc[s1 * 4 + h] + adst_h;
        float e2 = asrc[s2 * 4 + h] + adst_h;
        float e3 = asrc[s3 * 4 + h] + adst_h;
        float2 f0 = __half22float2(*(const __half2*)(xwh + (size_t)s0 * 128 + ch));
        float2 f1 = __half22float2(*(const __half2*)(xwh + (size_t)s1 * 128 + ch));
        float2 f2 = __half22float2(*(const __half2*)(xwh + (size_t)s2 * 128 + ch));
        float2 f3 = __half22float2(*(const __half2*)(xwh + (size_t)s3 * 128 + ch));
        e0 = (e0 > 0.f) ? e0 : SLOPE * e0;
        e1 = (e1 > 0.f) ? e1 : SLOPE * e1;
        e2 = (e2 > 0.f) ? e2 : SLOPE * e2;
        e3 = (e3 > 0.f) ? e3 : SLOPE * e3;
        float mn = fmaxf(fmaxf(m, fmaxf(e0, e1)), fmaxf(e2, e3));
        float sc = __expf(m - mn);
        float p0 = __expf(e0 - mn);
        float p1 = __expf(e1 - mn);
        float p2 = __expf(e2 - mn);
        float p3 = __expf(e3 - mn);
        s  = s  * sc + p0 + p1 + p2 + p3;
        a0 = a0 * sc + p0 * f0.x + p1 * f1.x + p2 * f2.x + p3 * f3.x;
        a1 = a1 * sc + p0 * f0.y + p1 * f1.y + p2 * f2.y + p3 * f3.y;
        m = mn;
    }
    for (; j < end; j++) {
        int s0 = csr[j];
        float e0 = asrc[s0 * 4 + h] + adst_h;
        float2 f0 = __half22float2(*(const __half2*)(xwh + (size_t)s0 * 128 + ch));
        e0 = (e0 > 0.f) ? e0 : SLOPE * e0;
        float mn = fmaxf(m, e0);
        float sc = __expf(m - mn);
        float p0 = __expf(e0 - mn);
        s  = s  * sc + p0;
        a0 = a0 * sc + p0 * f0.x;
        a1 = a1 * sc + p0 * f0.y;
        m = mn;
    }
    float inv = 1.f / s;
    float o0 = fmaxf(a0 * inv + b1[ch],     0.f);   // relu(h)
    float o1 = fmaxf(a1 * inv + b1[ch + 1], 0.f);

    // ---- fused GEMM2: per-lane partials, value-splitting butterfly ----
    float p[8];
    p[0] = o0 * wa0.x + o1 * wb0.x;  p[1] = o0 * wa0.y + o1 * wb0.y;
    p[2] = o0 * wa0.z + o1 * wb0.z;  p[3] = o0 * wa0.w + o1 * wb0.w;
    p[4] = o0 * wa1.x + o1 * wb1.x;  p[5] = o0 * wa1.y + o1 * wb1.y;
    p[6] = o0 * wa1.z + o1 * wb1.z;  p[7] = o0 * wa1.w + o1 * wb1.w;
    // mask 1: keep cc with bit0 == lane bit0
    float q[4];
    #pragma unroll
    for (int b = 0; b < 4; b++) {
        float keepv = (lane & 1) ? p[2 * b + 1] : p[2 * b];
        float sendv = (lane & 1) ? p[2 * b]     : p[2 * b + 1];
        q[b] = keepv + __shfl_xor(sendv, 1);
    }
    // mask 2: bit1
    float r2[2];
    #pragma unroll
    for (int b = 0; b < 2; b++) {
        float keepv = (lane & 2) ? q[2 * b + 1] : q[2 * b];
        float sendv = (lane & 2) ? q[2 * b]     : q[2 * b + 1];
        r2[b] = keepv + __shfl_xor(sendv, 2);
    }
    // mask 4: bit2
    {
        float keepv = (lane & 4) ? r2[1] : r2[0];
        float sendv = (lane & 4) ? r2[0] : r2[1];
        r2[0] = keepv + __shfl_xor(sendv, 4);
    }
    float f = r2[0];
    f += __shfl_xor(f, 8);
    f += __shfl_xor(f, 16);
    f += __shfl_xor(f, 32);
    // f = xw2[node][lane&7], identical across the 8 slot-groups
    if (lane < 8) xw2[node * 8 + lane] = f;
    float vs = f * a_s;
    float vd = f * a_d;
    vs += __shfl_xor(vs, 1); vs += __shfl_xor(vs, 2); vs += __shfl_xor(vs, 4);
    vd += __shfl_xor(vd, 1); vd += __shfl_xor(vd, 2); vd += __shfl_xor(vd, 4);
    if (lane == 0) { asrc2[node] = vs; adst2[node] = vd; }
}

// ---------------------------------------------------------------------------
// Layer-2 aggregation + log_softmax. ONE WAVE PER NODE:
// lane = slot(0..7)*8 + class(0..7). Each slot runs an independent online
// softmax over edges j = beg+slot, beg+slot+8, ...; slots merged by the
// associative online-softmax merge (masks 8/16/32). No divergence.
// ---------------------------------------------------------------------------
__global__ void k_agg2(const float* __restrict__ xw2, const float* __restrict__ asrc2,
                       const float* __restrict__ adst2, const int* __restrict__ offs,
                       const int* __restrict__ csr, const float* __restrict__ b2,
                       float* __restrict__ out, int N) {
    int node = (blockIdx.x * blockDim.x + threadIdx.x) >> 6;
    int lane = threadIdx.x & 63;
    if (node >= N) return;
    int slot = lane >> 3;
    int c    = lane & 7;
    float adst = adst2[node];
    int beg = offs[node], end = offs[node + 1];
    float m = -3.0e38f, s = 0.f, acc = 0.f;
    for (int j = beg + slot; j < end; j += 8) {
        int s0 = csr[j];
        float e0 = asrc2[s0] + adst;
        float v0 = xw2[s0 * 8 + c];
        e0 = (e0 > 0.f) ? e0 : SLOPE * e0;
        float mn = fmaxf(m, e0);
        float sc = __expf(m - mn);
        float p0 = __expf(e0 - mn);
        s   = s   * sc + p0;
        acc = acc * sc + p0 * v0;
        m = mn;
    }
    // merge the 8 slot-states (associative online-softmax merge)
    #pragma unroll
    for (int mk = 8; mk < 64; mk <<= 1) {
        float m2 = __shfl_xor(m, mk);
        float s2 = __shfl_xor(s, mk);
        float a2 = __shfl_xor(acc, mk);
        float mn = fmaxf(m, m2);
        float c1 = __expf(m - mn);
        float c2 = __expf(m2 - mn);
        s   = s * c1 + s2 * c2;
        acc = acc * c1 + a2 * c2;
        m = mn;
    }
    float o = acc / s + b2[c];
    // log_softmax across 8 classes (masks 1,2,4)
    float mx = o;
    mx = fmaxf(mx, __shfl_xor(mx, 1));
    mx = fmaxf(mx, __shfl_xor(mx, 2));
    mx = fmaxf(mx, __shfl_xor(mx, 4));
    float ex = __expf(o - mx);
    float se = ex;
    se += __shfl_xor(se, 1); se += __shfl_xor(se, 2); se += __shfl_xor(se, 4);
    if (slot == 0) out[node * 8 + c] = o - mx - __logf(se);
}

// ---------------------------------------------------------------------------
extern "C" void kernel_launch(void* const* d_in, const int* in_sizes, int n_in,
                              void* d_out, int out_size, void* d_ws, size_t ws_size,
                              hipStream_t stream) {
    const float* x   = (const float*)d_in[0];
    const int*   ei  = (const int*)d_in[1];
    const float* W1  = (const float*)d_in[2];
    const float* as1 = (const float*)d_in[3];
    const float* ad1 = (const float*)d_in[4];
    const float* b1  = (const float*)d_in[5];
    const float* W2  = (const float*)d_in[6];
    const float* as2 = (const float*)d_in[7];
    const float* ad2 = (const float*)d_in[8];
    const float* b2  = (const float*)d_in[9];
    float* out = (float*)d_out;

    int N = in_sizes[0] / F_IN;
    int E = in_sizes[1] / 2;
    int ET = E + N;                       // edges incl. self loops
    int NB = (N + 1023) / 1024;           // scan chunks (<=64 for N<=65536)

    // workspace carve
    char* p = (char*)d_ws;
    auto carve = [&](size_t bytes) { char* q = p; p += (bytes + 255) & ~(size_t)255; return (void*)q; };
    __half* xw1h = (__half*)carve((size_t)N * 128 * 2);
    float* asrc1 = (float*)carve((size_t)N * 4 * 4);
    float* adst1 = (float*)carve((size_t)N * 4 * 4);
    float* xw2   = (float*)carve((size_t)N * 8 * 4);
    float* asrc2 = (float*)carve((size_t)N * 4);
    float* adst2 = (float*)carve((size_t)N * 4);
    int*   deg   = (int*)carve((size_t)N * 4);
    int*   offs  = (int*)carve((size_t)(N + 1) * 4);
    int*   cur   = (int*)carve((size_t)N * 4);
    int*   bsum  = (int*)carve(64 * 4);
    int*   csr   = (int*)carve((size_t)ET * 4);

    // --- CSR build ---
    k_zero<<<(N + 255) / 256, 256, 0, stream>>>(deg, N);
    k_count<<<(E + 255) / 256, 256, 0, stream>>>(ei, deg, E);
    k_scan1<<<NB, 256, 0, stream>>>(deg, offs, bsum, N);
    k_scan2<<<1, 64, 0, stream>>>(bsum, offs, NB, N);
    k_scan3<<<NB, 256, 0, stream>>>(bsum, offs, cur, N);
    k_fill<<<(ET + 255) / 256, 256, 0, stream>>>(ei, cur, csr, E, N);

    // --- layer 1 (gemm1 + att1 fused) ---
    k_gemm1<<<(N + 15) / 16, 256, 0, stream>>>(x, W1, as1, ad1, xw1h, asrc1, adst1, N);

    // --- agg1 + gemm2 + att2 fused ---
    k_agg1<<<(N + 3) / 4, 256, 0, stream>>>(xw1h, asrc1, adst1, offs, csr, b1,
                                            W2, as2, ad2, xw2, asrc2, adst2, N);

    // --- layer 2 aggregation + log_softmax (1 wave / node) ---
    k_agg2<<<(N + 3) / 4, 256, 0, stream>>>(xw2, asrc2, adst2, offs, csr, b2, out, N);
}

// Round 6
// 294.576 us; speedup vs baseline: 1.0410x; 1.0410x over previous
//
#include <hip/hip_runtime.h>
#include <hip/hip_fp16.h>
#include <math.h>

#define F_IN   128
#define HEADS  4
#define HID    32
#define NCLS   8
#define SLOPE  0.2f

typedef _Float16 half8 __attribute__((ext_vector_type(8)));
typedef float    floatx4 __attribute__((ext_vector_type(4)));

// ---------------------------------------------------------------------------
// deg zero + W1 -> Wt (fp16, transposed [col][k]) prep, fused dispatch.
// blocks [0,ZB): zero deg; blocks [ZB,ZB+64): transpose/convert W1.
// ---------------------------------------------------------------------------
__global__ void k_zero_prep(int* __restrict__ deg, int N,
                            const float* __restrict__ W1, _Float16* __restrict__ Wt,
                            int ZB) {
    if ((int)blockIdx.x < ZB) {
        int i = blockIdx.x * 256 + threadIdx.x;
        if (i < N) deg[i] = 0;
    } else {
        int idx = (blockIdx.x - ZB) * 256 + threadIdx.x;   // [0, 16384)
        int c = idx >> 7, k = idx & 127;
        Wt[c * 128 + k] = (_Float16)W1[k * 128 + c];       // coalesced write
    }
}

// ---------------------------------------------------------------------------
// Degree count, reading edge_index directly.
// int64-layout detection: odd words of first 128 ints all zero iff int64.
// ---------------------------------------------------------------------------
__global__ void k_count(const int* __restrict__ ei, int* __restrict__ deg, int E) {
    int e = blockIdx.x * 256 + threadIdx.x;
    int probe = ei[2 * (threadIdx.x & 63) + 1];
    bool is64 = (__ballot(probe != 0) == 0ULL);
    if (e >= E) return;
    int d = is64 ? ei[2 * E + 2 * e] : ei[E + e];
    atomicAdd(&deg[d], 1);
}

// ---------------------------------------------------------------------------
// Hierarchical exclusive scan of (deg[i] + 1)  (self loop folded in).
// ---------------------------------------------------------------------------
__global__ void k_scan1(const int* __restrict__ deg, int* __restrict__ offs,
                        int* __restrict__ bsum, int N) {
    __shared__ int wtot[4];
    __shared__ int wbase[4];
    int tid = threadIdx.x;
    int lane = tid & 63, wid = tid >> 6;
    int i0 = blockIdx.x * 1024 + tid * 4;
    int v[4];
    #pragma unroll
    for (int k = 0; k < 4; k++) v[k] = (i0 + k < N) ? deg[i0 + k] + 1 : 0;
    int t = v[0] + v[1] + v[2] + v[3];
    int incl = t;
    #pragma unroll
    for (int off = 1; off < 64; off <<= 1) {
        int u = __shfl_up(incl, off, 64);
        if (lane >= off) incl += u;
    }
    if (lane == 63) wtot[wid] = incl;
    __syncthreads();
    if (tid == 0) {
        int run = 0;
        #pragma unroll
        for (int w = 0; w < 4; w++) { wbase[w] = run; run += wtot[w]; }
        bsum[blockIdx.x] = run;
    }
    __syncthreads();
    int ebase = wbase[wid] + incl - t;
    #pragma unroll
    for (int k = 0; k < 4; k++) {
        if (i0 + k < N) offs[i0 + k] = ebase;
        ebase += v[k];
    }
}

__global__ void k_scan2(int* __restrict__ bsum, int* __restrict__ offs, int NB, int N) {
    int lane = threadIdx.x;           // 64 threads
    int v = (lane < NB) ? bsum[lane] : 0;
    int incl = v;
    #pragma unroll
    for (int off = 1; off < 64; off <<= 1) {
        int u = __shfl_up(incl, off, 64);
        if (lane >= off) incl += u;
    }
    if (lane < NB) bsum[lane] = incl - v;
    if (lane == 63) offs[N] = incl;
}

__global__ void k_scan3(const int* __restrict__ bsum, int* __restrict__ offs,
                        int* __restrict__ cur, int N) {
    int add = bsum[blockIdx.x];
    int i0 = blockIdx.x * 1024 + threadIdx.x * 4;
    #pragma unroll
    for (int k = 0; k < 4; k++) {
        int i = i0 + k;
        if (i < N) { int o = offs[i] + add; offs[i] = o; cur[i] = o; }
    }
}

// ---------------------------------------------------------------------------
// FUSED: CSR fill (blocks < FB)  ∥  MFMA GEMM1 + att1 (blocks >= FB).
// Independent halves co-scheduled in one dispatch: gemm's MFMA/VALU work
// hides under fill's memory stalls.
//
// GEMM: one wave per 16 rows x 128 cols, K=128, v_mfma_f32_16x16x32_f16.
//   A: lane(q=lane>>4, t=lane&15) holds x[r0+t][kc*32+8q .. +8]  (fp32->fp16)
//   B: lane holds Wt[ct*16+t][kc*32+8q .. +8]   (Wt = W1^T, fp16)
//   C: lane holds C[q*4+reg][ct*16+t], reg=0..3
// att1: per head-pair epilogue reduce of acc*att over the 16 t-lanes.
// ---------------------------------------------------------------------------
__global__ void k_fill_gemm(const int* __restrict__ ei, int* __restrict__ cur,
                            int* __restrict__ csr, int E, int N, int FB,
                            const float* __restrict__ x, const _Float16* __restrict__ Wt,
                            const float* __restrict__ as1, const float* __restrict__ ad1,
                            _Float16* __restrict__ xwh, float* __restrict__ asrc,
                            float* __restrict__ adst) {
    if ((int)blockIdx.x < FB) {
        // ---------------- CSR fill ----------------
        int i = blockIdx.x * 256 + threadIdx.x;
        int probe = ei[2 * (threadIdx.x & 63) + 1];
        bool is64 = (__ballot(probe != 0) == 0ULL);
        if (i >= E + N) return;
        int s, d;
        if (i < E) {
            if (is64) { s = ei[2 * i]; d = ei[2 * E + 2 * i]; }
            else      { s = ei[i];     d = ei[E + i]; }
        } else { s = i - E; d = i - E; }          // self loop
        int pos = atomicAdd(&cur[d], 1);
        csr[pos] = s;
        return;
    }
    // ---------------- MFMA GEMM1 + att1 ----------------
    int gb   = blockIdx.x - FB;
    int wv   = threadIdx.x >> 6;
    int lane = threadIdx.x & 63;
    int r0   = gb * 64 + wv * 16;
    if (r0 >= N) return;
    int q = lane >> 4, t = lane & 15;
    int row = r0 + t;
    bool rok = row < N;

    half8 afr[4];
    #pragma unroll
    for (int kc = 0; kc < 4; kc++) {
        float4 u0 = make_float4(0.f, 0.f, 0.f, 0.f), u1 = u0;
        if (rok) {
            const float* xr = x + (size_t)row * 128 + kc * 32 + q * 8;
            u0 = *(const float4*)xr;
            u1 = *(const float4*)(xr + 4);
        }
        afr[kc][0] = (_Float16)u0.x; afr[kc][1] = (_Float16)u0.y;
        afr[kc][2] = (_Float16)u0.z; afr[kc][3] = (_Float16)u0.w;
        afr[kc][4] = (_Float16)u1.x; afr[kc][5] = (_Float16)u1.y;
        afr[kc][6] = (_Float16)u1.z; afr[kc][7] = (_Float16)u1.w;
    }

    float ps[4], pd[4];
    #pragma unroll
    for (int ct = 0; ct < 8; ct++) {
        floatx4 acc = {0.f, 0.f, 0.f, 0.f};
        #pragma unroll
        for (int kc = 0; kc < 4; kc++) {
            half8 b = *(const half8*)(Wt + (ct * 16 + t) * 128 + kc * 32 + q * 8);
            acc = __builtin_amdgcn_mfma_f32_16x16x32_f16(afr[kc], b, acc, 0, 0, 0);
        }
        int col = ct * 16 + t;
        float sa = as1[col], da = ad1[col];
        if ((ct & 1) == 0) {
            #pragma unroll
            for (int g = 0; g < 4; g++) { ps[g] = 0.f; pd[g] = 0.f; }
        }
        #pragma unroll
        for (int g = 0; g < 4; g++) {
            int r = r0 + q * 4 + g;
            if (r < N) xwh[(size_t)r * 128 + col] = (_Float16)acc[g];
            ps[g] += acc[g] * sa;
            pd[g] += acc[g] * da;
        }
        if (ct & 1) {
            int h = ct >> 1;
            #pragma unroll
            for (int g = 0; g < 4; g++) {
                float a = ps[g], d = pd[g];
                a += __shfl_xor(a, 1); d += __shfl_xor(d, 1);
                a += __shfl_xor(a, 2); d += __shfl_xor(d, 2);
                a += __shfl_xor(a, 4); d += __shfl_xor(d, 4);
                a += __shfl_xor(a, 8); d += __shfl_xor(d, 8);
                int r = r0 + q * 4 + g;
                if (t == 0 && r < N) { asrc[r * 4 + h] = a; adst[r * 4 + h] = d; }
            }
        }
    }
}

// ---------------------------------------------------------------------------
// Layer-1 aggregation + fused GEMM2/att2 epilogue. One wave per dst node.
// TWO-PHASE softmax:
//   Phase A: 16-edge-parallel max per head (no exp, no serial chain).
//   Phase B: 1 exp/edge, no rescale chain, 4-edge unroll.
// Epilogue: W2 in registers, value-splitting butterfly (10 shuffles).
// ---------------------------------------------------------------------------
__global__ void k_agg1(const _Float16* __restrict__ xwh, const float* __restrict__ asrc,
                       const float* __restrict__ adst, const int* __restrict__ offs,
                       const int* __restrict__ csr, const float* __restrict__ b1,
                       const float* __restrict__ W2, const float* __restrict__ as2,
                       const float* __restrict__ ad2, float* __restrict__ xw2,
                       float* __restrict__ asrc2, float* __restrict__ adst2, int N) {
    int node = (blockIdx.x * blockDim.x + threadIdx.x) >> 6;
    int lane = threadIdx.x & 63;
    if (node >= N) return;
    int h = lane >> 4;
    int t = lane & 15;
    int ch = h * 32 + 2 * t;

    const float4* w2p = (const float4*)(W2 + ch * 8);
    float4 wa0 = w2p[0], wa1 = w2p[1];
    float4 wb0 = w2p[2], wb1 = w2p[3];
    float a_s = as2[lane & 7];
    float a_d = ad2[lane & 7];

    float adst_h = adst[node * 4 + h];
    int beg = offs[node], end = offs[node + 1];

    // ---- Phase A: per-head max, edge-parallel across 16 lanes ----
    float mx = -3.0e38f;
    for (int j = beg + t; j < end; j += 16) {
        float e = asrc[csr[j] * 4 + h] + adst_h;
        e = (e > 0.f) ? e : SLOPE * e;
        mx = fmaxf(mx, e);
    }
    mx = fmaxf(mx, __shfl_xor(mx, 1));
    mx = fmaxf(mx, __shfl_xor(mx, 2));
    mx = fmaxf(mx, __shfl_xor(mx, 4));
    mx = fmaxf(mx, __shfl_xor(mx, 8));

    // ---- Phase B: accumulate with known max (no rescale chain) ----
    float s = 0.f, a0 = 0.f, a1 = 0.f;
    int j = beg;
    for (; j + 4 <= end; j += 4) {
        int s0 = csr[j], s1 = csr[j + 1], s2 = csr[j + 2], s3 = csr[j + 3];
        float e0 = asrc[s0 * 4 + h] + adst_h;
        float e1 = asrc[s1 * 4 + h] + adst_h;
        float e2 = asrc[s2 * 4 + h] + adst_h;
        float e3 = asrc[s3 * 4 + h] + adst_h;
        float2 f0 = __half22float2(*(const __half2*)(xwh + (size_t)s0 * 128 + ch));
        float2 f1 = __half22float2(*(const __half2*)(xwh + (size_t)s1 * 128 + ch));
        float2 f2 = __half22float2(*(const __half2*)(xwh + (size_t)s2 * 128 + ch));
        float2 f3 = __half22float2(*(const __half2*)(xwh + (size_t)s3 * 128 + ch));
        e0 = (e0 > 0.f) ? e0 : SLOPE * e0;
        e1 = (e1 > 0.f) ? e1 : SLOPE * e1;
        e2 = (e2 > 0.f) ? e2 : SLOPE * e2;
        e3 = (e3 > 0.f) ? e3 : SLOPE * e3;
        float p0 = __expf(e0 - mx);
        float p1 = __expf(e1 - mx);
        float p2 = __expf(e2 - mx);
        float p3 = __expf(e3 - mx);
        s  += p0 + p1 + p2 + p3;
        a0 += p0 * f0.x + p1 * f1.x + p2 * f2.x + p3 * f3.x;
        a1 += p0 * f0.y + p1 * f1.y + p2 * f2.y + p3 * f3.y;
    }
    for (; j < end; j++) {
        int s0 = csr[j];
        float e0 = asrc[s0 * 4 + h] + adst_h;
        float2 f0 = __half22float2(*(const __half2*)(xwh + (size_t)s0 * 128 + ch));
        e0 = (e0 > 0.f) ? e0 : SLOPE * e0;
        float p0 = __expf(e0 - mx);
        s  += p0;
        a0 += p0 * f0.x;
        a1 += p0 * f0.y;
    }
    float inv = 1.f / s;
    float o0 = fmaxf(a0 * inv + b1[ch],     0.f);   // relu(h)
    float o1 = fmaxf(a1 * inv + b1[ch + 1], 0.f);

    // ---- fused GEMM2: per-lane partials, value-splitting butterfly ----
    float p[8];
    p[0] = o0 * wa0.x + o1 * wb0.x;  p[1] = o0 * wa0.y + o1 * wb0.y;
    p[2] = o0 * wa0.z + o1 * wb0.z;  p[3] = o0 * wa0.w + o1 * wb0.w;
    p[4] = o0 * wa1.x + o1 * wb1.x;  p[5] = o0 * wa1.y + o1 * wb1.y;
    p[6] = o0 * wa1.z + o1 * wb1.z;  p[7] = o0 * wa1.w + o1 * wb1.w;
    float qq[4];
    #pragma unroll
    for (int b = 0; b < 4; b++) {
        float keepv = (lane & 1) ? p[2 * b + 1] : p[2 * b];
        float sendv = (lane & 1) ? p[2 * b]     : p[2 * b + 1];
        qq[b] = keepv + __shfl_xor(sendv, 1);
    }
    float r2[2];
    #pragma unroll
    for (int b = 0; b < 2; b++) {
        float keepv = (lane & 2) ? qq[2 * b + 1] : qq[2 * b];
        float sendv = (lane & 2) ? qq[2 * b]     : qq[2 * b + 1];
        r2[b] = keepv + __shfl_xor(sendv, 2);
    }
    {
        float keepv = (lane & 4) ? r2[1] : r2[0];
        float sendv = (lane & 4) ? r2[0] : r2[1];
        r2[0] = keepv + __shfl_xor(sendv, 4);
    }
    float f = r2[0];
    f += __shfl_xor(f, 8);
    f += __shfl_xor(f, 16);
    f += __shfl_xor(f, 32);
    if (lane < 8) xw2[node * 8 + lane] = f;
    float vs = f * a_s;
    float vd = f * a_d;
    vs += __shfl_xor(vs, 1); vs += __shfl_xor(vs, 2); vs += __shfl_xor(vs, 4);
    vd += __shfl_xor(vd, 1); vd += __shfl_xor(vd, 2); vd += __shfl_xor(vd, 4);
    if (lane == 0) { asrc2[node] = vs; adst2[node] = vd; }
}

// ---------------------------------------------------------------------------
// Layer-2 aggregation + log_softmax. One wave per node:
// lane = slot(0..7)*8 + class(0..7); slot-parallel online softmax, merged
// by the associative online-softmax merge (masks 8/16/32).
// ---------------------------------------------------------------------------
__global__ void k_agg2(const float* __restrict__ xw2, const float* __restrict__ asrc2,
                       const float* __restrict__ adst2, const int* __restrict__ offs,
                       const int* __restrict__ csr, const float* __restrict__ b2,
                       float* __restrict__ out, int N) {
    int node = (blockIdx.x * blockDim.x + threadIdx.x) >> 6;
    int lane = threadIdx.x & 63;
    if (node >= N) return;
    int slot = lane >> 3;
    int c    = lane & 7;
    float adst = adst2[node];
    int beg = offs[node], end = offs[node + 1];
    float m = -3.0e38f, s = 0.f, acc = 0.f;
    for (int j = beg + slot; j < end; j += 8) {
        int s0 = csr[j];
        float e0 = asrc2[s0] + adst;
        float v0 = xw2[s0 * 8 + c];
        e0 = (e0 > 0.f) ? e0 : SLOPE * e0;
        float mn = fmaxf(m, e0);
        float sc = __expf(m - mn);
        float p0 = __expf(e0 - mn);
        s   = s   * sc + p0;
        acc = acc * sc + p0 * v0;
        m = mn;
    }
    #pragma unroll
    for (int mk = 8; mk < 64; mk <<= 1) {
        float m2 = __shfl_xor(m, mk);
        float s2 = __shfl_xor(s, mk);
        float a2 = __shfl_xor(acc, mk);
        float mn = fmaxf(m, m2);
        float c1 = __expf(m - mn);
        float c2 = __expf(m2 - mn);
        s   = s * c1 + s2 * c2;
        acc = acc * c1 + a2 * c2;
        m = mn;
    }
    float o = acc / s + b2[c];
    float mxv = o;
    mxv = fmaxf(mxv, __shfl_xor(mxv, 1));
    mxv = fmaxf(mxv, __shfl_xor(mxv, 2));
    mxv = fmaxf(mxv, __shfl_xor(mxv, 4));
    float ex = __expf(o - mxv);
    float se = ex;
    se += __shfl_xor(se, 1); se += __shfl_xor(se, 2); se += __shfl_xor(se, 4);
    if (slot == 0) out[node * 8 + c] = o - mxv - __logf(se);
}

// ---------------------------------------------------------------------------
extern "C" void kernel_launch(void* const* d_in, const int* in_sizes, int n_in,
                              void* d_out, int out_size, void* d_ws, size_t ws_size,
                              hipStream_t stream) {
    const float* x   = (const float*)d_in[0];
    const int*   ei  = (const int*)d_in[1];
    const float* W1  = (const float*)d_in[2];
    const float* as1 = (const float*)d_in[3];
    const float* ad1 = (const float*)d_in[4];
    const float* b1  = (const float*)d_in[5];
    const float* W2  = (const float*)d_in[6];
    const float* as2 = (const float*)d_in[7];
    const float* ad2 = (const float*)d_in[8];
    const float* b2  = (const float*)d_in[9];
    float* out = (float*)d_out;

    int N = in_sizes[0] / F_IN;
    int E = in_sizes[1] / 2;
    int ET = E + N;                       // edges incl. self loops
    int NB = (N + 1023) / 1024;           // scan chunks (<=64 for N<=65536)
    int ZB = (N + 255) / 256;             // zero blocks
    int FB = (ET + 255) / 256;            // fill blocks
    int GB = (N + 63) / 64;               // gemm blocks (64 rows each)

    // workspace carve
    char* p = (char*)d_ws;
    auto carve = [&](size_t bytes) { char* q = p; p += (bytes + 255) & ~(size_t)255; return (void*)q; };
    _Float16* xw1h = (_Float16*)carve((size_t)N * 128 * 2);
    _Float16* Wt   = (_Float16*)carve(128 * 128 * 2);
    float* asrc1 = (float*)carve((size_t)N * 4 * 4);
    float* adst1 = (float*)carve((size_t)N * 4 * 4);
    float* xw2   = (float*)carve((size_t)N * 8 * 4);
    float* asrc2 = (float*)carve((size_t)N * 4);
    float* adst2 = (float*)carve((size_t)N * 4);
    int*   deg   = (int*)carve((size_t)N * 4);
    int*   offs  = (int*)carve((size_t)(N + 1) * 4);
    int*   cur   = (int*)carve((size_t)N * 4);
    int*   bsum  = (int*)carve(64 * 4);
    int*   csr   = (int*)carve((size_t)ET * 4);

    // --- prep: deg zero ∥ W1->Wt fp16 transpose ---
    k_zero_prep<<<ZB + 64, 256, 0, stream>>>(deg, N, W1, Wt, ZB);
    k_count<<<(E + 255) / 256, 256, 0, stream>>>(ei, deg, E);
    k_scan1<<<NB, 256, 0, stream>>>(deg, offs, bsum, N);
    k_scan2<<<1, 64, 0, stream>>>(bsum, offs, NB, N);
    k_scan3<<<NB, 256, 0, stream>>>(bsum, offs, cur, N);

    // --- CSR fill ∥ MFMA GEMM1+att1 (independent, one dispatch) ---
    k_fill_gemm<<<FB + GB, 256, 0, stream>>>(ei, cur, csr, E, N, FB,
                                             x, Wt, as1, ad1, xw1h, asrc1, adst1);

    // --- agg1 + gemm2 + att2 fused ---
    k_agg1<<<(N + 3) / 4, 256, 0, stream>>>(xw1h, asrc1, adst1, offs, csr, b1,
                                            W2, as2, ad2, xw2, asrc2, adst2, N);

    // --- layer 2 aggregation + log_softmax (1 wave / node) ---
    k_agg2<<<(N + 3) / 4, 256, 0, stream>>>(xw2, asrc2, adst2, offs, csr, b2, out, N);
}

// Round 7
// 286.831 us; speedup vs baseline: 1.0692x; 1.0270x over previous
//
#include <hip/hip_runtime.h>
#include <hip/hip_fp16.h>
#include <math.h>

#define F_IN   128
#define HEADS  4
#define HID    32
#define NCLS   8
#define SLOPE  0.2f

typedef _Float16 half8 __attribute__((ext_vector_type(8)));
typedef float    floatx4 __attribute__((ext_vector_type(4)));

// ---------------------------------------------------------------------------
// deg zero + W1 -> Wt (fp16, transposed [col][k]) prep, fused dispatch.
// ---------------------------------------------------------------------------
__global__ void k_zero_prep(int* __restrict__ deg, int N,
                            const float* __restrict__ W1, _Float16* __restrict__ Wt,
                            int ZB) {
    if ((int)blockIdx.x < ZB) {
        int i = blockIdx.x * 256 + threadIdx.x;
        if (i < N) deg[i] = 0;
    } else {
        int idx = (blockIdx.x - ZB) * 256 + threadIdx.x;   // [0, 16384)
        int c = idx >> 7, k = idx & 127;
        Wt[c * 128 + k] = (_Float16)W1[k * 128 + c];       // coalesced write
    }
}

// ---------------------------------------------------------------------------
// FUSED: partitioned degree count (blocks < 8*CPB)  ∥  MFMA GEMM1+att1.
//
// Count partitioning: partition p = blockIdx&7 owns dst in [p*Npp,(p+1)*Npp).
// With round-robin blockIdx->XCD, each partition's deg slice (~25 KB) stays
// resident in ONE XCD's L2 -> no cross-XCD atomic line bouncing. Every
// partition streams all E dst words (coalesced, cheap); only in-range ones
// count.
//
// GEMM: one wave per 16 rows x 128 cols, K=128, v_mfma_f32_16x16x32_f16.
//   A: lane(q=lane>>4, t=lane&15) holds x[r0+t][kc*32+8q .. +8]  (fp32->fp16)
//   B: lane holds Wt[ct*16+t][kc*32+8q .. +8]   (Wt = W1^T, fp16)
//   C: lane holds C[q*4+reg][ct*16+t]
// att1 dots reduced from fp32 accumulators in the epilogue.
// ---------------------------------------------------------------------------
__global__ void k_count_gemm(const int* __restrict__ ei, int* __restrict__ deg,
                             int E, int N, int CPB,
                             const float* __restrict__ x, const _Float16* __restrict__ Wt,
                             const float* __restrict__ as1, const float* __restrict__ ad1,
                             _Float16* __restrict__ xwh, float* __restrict__ asrc,
                             float* __restrict__ adst) {
    int ncb = CPB * 8;
    if ((int)blockIdx.x < ncb) {
        // ---------------- partitioned count ----------------
        int p  = blockIdx.x & 7;
        int bp = blockIdx.x >> 3;
        int Npp = (N + 7) >> 3;
        int lo = p * Npp;
        int hi = lo + Npp; if (hi > N) hi = N;
        int probe = ei[2 * (threadIdx.x & 63) + 1];
        bool is64 = (__ballot(probe != 0) == 0ULL);
        int stride = CPB * 256;
        for (int e = bp * 256 + threadIdx.x; e < E; e += stride) {
            int d = is64 ? ei[2 * E + 2 * e] : ei[E + e];
            if (d >= lo && d < hi) atomicAdd(&deg[d], 1);
        }
        return;
    }
    // ---------------- MFMA GEMM1 + att1 ----------------
    int gb   = blockIdx.x - ncb;
    int wv   = threadIdx.x >> 6;
    int lane = threadIdx.x & 63;
    int r0   = gb * 64 + wv * 16;
    if (r0 >= N) return;
    int q = lane >> 4, t = lane & 15;
    int row = r0 + t;
    bool rok = row < N;

    half8 afr[4];
    #pragma unroll
    for (int kc = 0; kc < 4; kc++) {
        float4 u0 = make_float4(0.f, 0.f, 0.f, 0.f), u1 = u0;
        if (rok) {
            const float* xr = x + (size_t)row * 128 + kc * 32 + q * 8;
            u0 = *(const float4*)xr;
            u1 = *(const float4*)(xr + 4);
        }
        afr[kc][0] = (_Float16)u0.x; afr[kc][1] = (_Float16)u0.y;
        afr[kc][2] = (_Float16)u0.z; afr[kc][3] = (_Float16)u0.w;
        afr[kc][4] = (_Float16)u1.x; afr[kc][5] = (_Float16)u1.y;
        afr[kc][6] = (_Float16)u1.z; afr[kc][7] = (_Float16)u1.w;
    }

    float ps[4], pd[4];
    #pragma unroll
    for (int ct = 0; ct < 8; ct++) {
        floatx4 acc = {0.f, 0.f, 0.f, 0.f};
        #pragma unroll
        for (int kc = 0; kc < 4; kc++) {
            half8 b = *(const half8*)(Wt + (ct * 16 + t) * 128 + kc * 32 + q * 8);
            acc = __builtin_amdgcn_mfma_f32_16x16x32_f16(afr[kc], b, acc, 0, 0, 0);
        }
        int col = ct * 16 + t;
        float sa = as1[col], da = ad1[col];
        if ((ct & 1) == 0) {
            #pragma unroll
            for (int g = 0; g < 4; g++) { ps[g] = 0.f; pd[g] = 0.f; }
        }
        #pragma unroll
        for (int g = 0; g < 4; g++) {
            int r = r0 + q * 4 + g;
            if (r < N) xwh[(size_t)r * 128 + col] = (_Float16)acc[g];
            ps[g] += acc[g] * sa;
            pd[g] += acc[g] * da;
        }
        if (ct & 1) {
            int h = ct >> 1;
            #pragma unroll
            for (int g = 0; g < 4; g++) {
                float a = ps[g], d = pd[g];
                a += __shfl_xor(a, 1); d += __shfl_xor(d, 1);
                a += __shfl_xor(a, 2); d += __shfl_xor(d, 2);
                a += __shfl_xor(a, 4); d += __shfl_xor(d, 4);
                a += __shfl_xor(a, 8); d += __shfl_xor(d, 8);
                int r = r0 + q * 4 + g;
                if (t == 0 && r < N) { asrc[r * 4 + h] = a; adst[r * 4 + h] = d; }
            }
        }
    }
}

// ---------------------------------------------------------------------------
// Hierarchical exclusive scan of (deg[i] + 1)  (self loop folded in).
// ---------------------------------------------------------------------------
__global__ void k_scan1(const int* __restrict__ deg, int* __restrict__ offs,
                        int* __restrict__ bsum, int N) {
    __shared__ int wtot[4];
    __shared__ int wbase[4];
    int tid = threadIdx.x;
    int lane = tid & 63, wid = tid >> 6;
    int i0 = blockIdx.x * 1024 + tid * 4;
    int v[4];
    #pragma unroll
    for (int k = 0; k < 4; k++) v[k] = (i0 + k < N) ? deg[i0 + k] + 1 : 0;
    int t = v[0] + v[1] + v[2] + v[3];
    int incl = t;
    #pragma unroll
    for (int off = 1; off < 64; off <<= 1) {
        int u = __shfl_up(incl, off, 64);
        if (lane >= off) incl += u;
    }
    if (lane == 63) wtot[wid] = incl;
    __syncthreads();
    if (tid == 0) {
        int run = 0;
        #pragma unroll
        for (int w = 0; w < 4; w++) { wbase[w] = run; run += wtot[w]; }
        bsum[blockIdx.x] = run;
    }
    __syncthreads();
    int ebase = wbase[wid] + incl - t;
    #pragma unroll
    for (int k = 0; k < 4; k++) {
        if (i0 + k < N) offs[i0 + k] = ebase;
        ebase += v[k];
    }
}

__global__ void k_scan2(int* __restrict__ bsum, int* __restrict__ offs, int NB, int N) {
    int lane = threadIdx.x;           // 64 threads
    int v = (lane < NB) ? bsum[lane] : 0;
    int incl = v;
    #pragma unroll
    for (int off = 1; off < 64; off <<= 1) {
        int u = __shfl_up(incl, off, 64);
        if (lane >= off) incl += u;
    }
    if (lane < NB) bsum[lane] = incl - v;
    if (lane == 63) offs[N] = incl;
}

__global__ void k_scan3(const int* __restrict__ bsum, int* __restrict__ offs,
                        int* __restrict__ cur, int N) {
    int add = bsum[blockIdx.x];
    int i0 = blockIdx.x * 1024 + threadIdx.x * 4;
    #pragma unroll
    for (int k = 0; k < 4; k++) {
        int i = i0 + k;
        if (i < N) { int o = offs[i] + add; offs[i] = o; cur[i] = o; }
    }
}

// ---------------------------------------------------------------------------
// Partitioned CSR fill: partition p = blockIdx&7 owns dst range
// [p*Npp,(p+1)*Npp) -> its csr/cur slice is written by one XCD's L2 only
// (no cross-XCD line bouncing on the scattered 4B stores). Every partition
// streams all dst words; src is read only for owned edges.
// ---------------------------------------------------------------------------
__global__ void k_fill(const int* __restrict__ ei, int* __restrict__ cur,
                       int* __restrict__ csr, int E, int N, int FPB) {
    int p  = blockIdx.x & 7;
    int bp = blockIdx.x >> 3;
    int Npp = (N + 7) >> 3;
    int lo = p * Npp;
    int hi = lo + Npp; if (hi > N) hi = N;
    int probe = ei[2 * (threadIdx.x & 63) + 1];
    bool is64 = (__ballot(probe != 0) == 0ULL);
    int ET = E + N;
    int stride = FPB * 256;
    for (int i = bp * 256 + threadIdx.x; i < ET; i += stride) {
        int d;
        if (i < E) d = is64 ? ei[2 * E + 2 * i] : ei[E + i];
        else       d = i - E;                       // self loop
        if (d < lo || d >= hi) continue;
        int s;
        if (i < E) s = is64 ? ei[2 * i] : ei[i];
        else       s = d;
        int pos = atomicAdd(&cur[d], 1);
        csr[pos] = s;
    }
}

// ---------------------------------------------------------------------------
// Layer-1 aggregation + fused GEMM2/att2 epilogue. One wave per dst node.
// Two-phase softmax (phase A: edge-parallel max; phase B: no rescale chain).
// Epilogue: W2 in registers, value-splitting butterfly.
// ---------------------------------------------------------------------------
__global__ void k_agg1(const _Float16* __restrict__ xwh, const float* __restrict__ asrc,
                       const float* __restrict__ adst, const int* __restrict__ offs,
                       const int* __restrict__ csr, const float* __restrict__ b1,
                       const float* __restrict__ W2, const float* __restrict__ as2,
                       const float* __restrict__ ad2, float* __restrict__ xw2,
                       float* __restrict__ asrc2, float* __restrict__ adst2, int N) {
    int node = (blockIdx.x * blockDim.x + threadIdx.x) >> 6;
    int lane = threadIdx.x & 63;
    if (node >= N) return;
    int h = lane >> 4;
    int t = lane & 15;
    int ch = h * 32 + 2 * t;

    const float4* w2p = (const float4*)(W2 + ch * 8);
    float4 wa0 = w2p[0], wa1 = w2p[1];
    float4 wb0 = w2p[2], wb1 = w2p[3];
    float a_s = as2[lane & 7];
    float a_d = ad2[lane & 7];

    float adst_h = adst[node * 4 + h];
    int beg = offs[node], end = offs[node + 1];

    // ---- Phase A: per-head max, edge-parallel across 16 lanes ----
    float mx = -3.0e38f;
    for (int j = beg + t; j < end; j += 16) {
        float e = asrc[csr[j] * 4 + h] + adst_h;
        e = (e > 0.f) ? e : SLOPE * e;
        mx = fmaxf(mx, e);
    }
    mx = fmaxf(mx, __shfl_xor(mx, 1));
    mx = fmaxf(mx, __shfl_xor(mx, 2));
    mx = fmaxf(mx, __shfl_xor(mx, 4));
    mx = fmaxf(mx, __shfl_xor(mx, 8));

    // ---- Phase B: accumulate with known max (no rescale chain) ----
    float s = 0.f, a0 = 0.f, a1 = 0.f;
    int j = beg;
    for (; j + 4 <= end; j += 4) {
        int s0 = csr[j], s1 = csr[j + 1], s2 = csr[j + 2], s3 = csr[j + 3];
        float e0 = asrc[s0 * 4 + h] + adst_h;
        float e1 = asrc[s1 * 4 + h] + adst_h;
        float e2 = asrc[s2 * 4 + h] + adst_h;
        float e3 = asrc[s3 * 4 + h] + adst_h;
        float2 f0 = __half22float2(*(const __half2*)(xwh + (size_t)s0 * 128 + ch));
        float2 f1 = __half22float2(*(const __half2*)(xwh + (size_t)s1 * 128 + ch));
        float2 f2 = __half22float2(*(const __half2*)(xwh + (size_t)s2 * 128 + ch));
        float2 f3 = __half22float2(*(const __half2*)(xwh + (size_t)s3 * 128 + ch));
        e0 = (e0 > 0.f) ? e0 : SLOPE * e0;
        e1 = (e1 > 0.f) ? e1 : SLOPE * e1;
        e2 = (e2 > 0.f) ? e2 : SLOPE * e2;
        e3 = (e3 > 0.f) ? e3 : SLOPE * e3;
        float p0 = __expf(e0 - mx);
        float p1 = __expf(e1 - mx);
        float p2 = __expf(e2 - mx);
        float p3 = __expf(e3 - mx);
        s  += p0 + p1 + p2 + p3;
        a0 += p0 * f0.x + p1 * f1.x + p2 * f2.x + p3 * f3.x;
        a1 += p0 * f0.y + p1 * f1.y + p2 * f2.y + p3 * f3.y;
    }
    for (; j < end; j++) {
        int s0 = csr[j];
        float e0 = asrc[s0 * 4 + h] + adst_h;
        float2 f0 = __half22float2(*(const __half2*)(xwh + (size_t)s0 * 128 + ch));
        e0 = (e0 > 0.f) ? e0 : SLOPE * e0;
        float p0 = __expf(e0 - mx);
        s  += p0;
        a0 += p0 * f0.x;
        a1 += p0 * f0.y;
    }
    float inv = 1.f / s;
    float o0 = fmaxf(a0 * inv + b1[ch],     0.f);   // relu(h)
    float o1 = fmaxf(a1 * inv + b1[ch + 1], 0.f);

    // ---- fused GEMM2: per-lane partials, value-splitting butterfly ----
    float p[8];
    p[0] = o0 * wa0.x + o1 * wb0.x;  p[1] = o0 * wa0.y + o1 * wb0.y;
    p[2] = o0 * wa0.z + o1 * wb0.z;  p[3] = o0 * wa0.w + o1 * wb0.w;
    p[4] = o0 * wa1.x + o1 * wb1.x;  p[5] = o0 * wa1.y + o1 * wb1.y;
    p[6] = o0 * wa1.z + o1 * wb1.z;  p[7] = o0 * wa1.w + o1 * wb1.w;
    float qq[4];
    #pragma unroll
    for (int b = 0; b < 4; b++) {
        float keepv = (lane & 1) ? p[2 * b + 1] : p[2 * b];
        float sendv = (lane & 1) ? p[2 * b]     : p[2 * b + 1];
        qq[b] = keepv + __shfl_xor(sendv, 1);
    }
    float r2[2];
    #pragma unroll
    for (int b = 0; b < 2; b++) {
        float keepv = (lane & 2) ? qq[2 * b + 1] : qq[2 * b];
        float sendv = (lane & 2) ? qq[2 * b]     : qq[2 * b + 1];
        r2[b] = keepv + __shfl_xor(sendv, 2);
    }
    {
        float keepv = (lane & 4) ? r2[1] : r2[0];
        float sendv = (lane & 4) ? r2[0] : r2[1];
        r2[0] = keepv + __shfl_xor(sendv, 4);
    }
    float f = r2[0];
    f += __shfl_xor(f, 8);
    f += __shfl_xor(f, 16);
    f += __shfl_xor(f, 32);
    if (lane < 8) xw2[node * 8 + lane] = f;
    float vs = f * a_s;
    float vd = f * a_d;
    vs += __shfl_xor(vs, 1); vs += __shfl_xor(vs, 2); vs += __shfl_xor(vs, 4);
    vd += __shfl_xor(vd, 1); vd += __shfl_xor(vd, 2); vd += __shfl_xor(vd, 4);
    if (lane == 0) { asrc2[node] = vs; adst2[node] = vd; }
}

// ---------------------------------------------------------------------------
// Layer-2 aggregation + log_softmax. One wave per node:
// lane = slot(0..7)*8 + class(0..7); slot-parallel online softmax, merged
// by the associative online-softmax merge (masks 8/16/32).
// ---------------------------------------------------------------------------
__global__ void k_agg2(const float* __restrict__ xw2, const float* __restrict__ asrc2,
                       const float* __restrict__ adst2, const int* __restrict__ offs,
                       const int* __restrict__ csr, const float* __restrict__ b2,
                       float* __restrict__ out, int N) {
    int node = (blockIdx.x * blockDim.x + threadIdx.x) >> 6;
    int lane = threadIdx.x & 63;
    if (node >= N) return;
    int slot = lane >> 3;
    int c    = lane & 7;
    float adst = adst2[node];
    int beg = offs[node], end = offs[node + 1];
    float m = -3.0e38f, s = 0.f, acc = 0.f;
    for (int j = beg + slot; j < end; j += 8) {
        int s0 = csr[j];
        float e0 = asrc2[s0] + adst;
        float v0 = xw2[s0 * 8 + c];
        e0 = (e0 > 0.f) ? e0 : SLOPE * e0;
        float mn = fmaxf(m, e0);
        float sc = __expf(m - mn);
        float p0 = __expf(e0 - mn);
        s   = s   * sc + p0;
        acc = acc * sc + p0 * v0;
        m = mn;
    }
    #pragma unroll
    for (int mk = 8; mk < 64; mk <<= 1) {
        float m2 = __shfl_xor(m, mk);
        float s2 = __shfl_xor(s, mk);
        float a2 = __shfl_xor(acc, mk);
        float mn = fmaxf(m, m2);
        float c1 = __expf(m - mn);
        float c2 = __expf(m2 - mn);
        s   = s * c1 + s2 * c2;
        acc = acc * c1 + a2 * c2;
        m = mn;
    }
    float o = acc / s + b2[c];
    float mxv = o;
    mxv = fmaxf(mxv, __shfl_xor(mxv, 1));
    mxv = fmaxf(mxv, __shfl_xor(mxv, 2));
    mxv = fmaxf(mxv, __shfl_xor(mxv, 4));
    float ex = __expf(o - mxv);
    float se = ex;
    se += __shfl_xor(se, 1); se += __shfl_xor(se, 2); se += __shfl_xor(se, 4);
    if (slot == 0) out[node * 8 + c] = o - mxv - __logf(se);
}

// ---------------------------------------------------------------------------
extern "C" void kernel_launch(void* const* d_in, const int* in_sizes, int n_in,
                              void* d_out, int out_size, void* d_ws, size_t ws_size,
                              hipStream_t stream) {
    const float* x   = (const float*)d_in[0];
    const int*   ei  = (const int*)d_in[1];
    const float* W1  = (const float*)d_in[2];
    const float* as1 = (const float*)d_in[3];
    const float* ad1 = (const float*)d_in[4];
    const float* b1  = (const float*)d_in[5];
    const float* W2  = (const float*)d_in[6];
    const float* as2 = (const float*)d_in[7];
    const float* ad2 = (const float*)d_in[8];
    const float* b2  = (const float*)d_in[9];
    float* out = (float*)d_out;

    int N = in_sizes[0] / F_IN;
    int E = in_sizes[1] / 2;
    int ET = E + N;                       // edges incl. self loops
    int NB = (N + 1023) / 1024;           // scan chunks (<=64 for N<=65536)
    int ZB = (N + 255) / 256;             // zero blocks
    int GB = (N + 63) / 64;               // gemm blocks (64 rows each)
    int CPB = 256;                        // count blocks per partition
    int FPB = 256;                        // fill blocks per partition

    // workspace carve
    char* p = (char*)d_ws;
    auto carve = [&](size_t bytes) { char* q = p; p += (bytes + 255) & ~(size_t)255; return (void*)q; };
    _Float16* xw1h = (_Float16*)carve((size_t)N * 128 * 2);
    _Float16* Wt   = (_Float16*)carve(128 * 128 * 2);
    float* asrc1 = (float*)carve((size_t)N * 4 * 4);
    float* adst1 = (float*)carve((size_t)N * 4 * 4);
    float* xw2   = (float*)carve((size_t)N * 8 * 4);
    float* asrc2 = (float*)carve((size_t)N * 4);
    float* adst2 = (float*)carve((size_t)N * 4);
    int*   deg   = (int*)carve((size_t)N * 4);
    int*   offs  = (int*)carve((size_t)(N + 1) * 4);
    int*   cur   = (int*)carve((size_t)N * 4);
    int*   bsum  = (int*)carve(64 * 4);
    int*   csr   = (int*)carve((size_t)ET * 4);

    // --- prep: deg zero ∥ W1->Wt fp16 transpose ---
    k_zero_prep<<<ZB + 64, 256, 0, stream>>>(deg, N, W1, Wt, ZB);

    // --- partitioned count ∥ MFMA GEMM1+att1 ---
    k_count_gemm<<<CPB * 8 + GB, 256, 0, stream>>>(ei, deg, E, N, CPB,
                                                   x, Wt, as1, ad1, xw1h, asrc1, adst1);

    // --- hierarchical scan + cursor ---
    k_scan1<<<NB, 256, 0, stream>>>(deg, offs, bsum, N);
    k_scan2<<<1, 64, 0, stream>>>(bsum, offs, NB, N);
    k_scan3<<<NB, 256, 0, stream>>>(bsum, offs, cur, N);

    // --- partitioned CSR fill ---
    k_fill<<<FPB * 8, 256, 0, stream>>>(ei, cur, csr, E, N, FPB);

    // --- agg1 + gemm2 + att2 fused ---
    k_agg1<<<(N + 3) / 4, 256, 0, stream>>>(xw1h, asrc1, adst1, offs, csr, b1,
                                            W2, as2, ad2, xw2, asrc2, adst2, N);

    // --- layer 2 aggregation + log_softmax (1 wave / node) ---
    k_agg2<<<(N + 3) / 4, 256, 0, stream>>>(xw2, asrc2, adst2, offs, csr, b2, out, N);
}

// Round 9
// 231.960 us; speedup vs baseline: 1.3221x; 1.2366x over previous
//
#include <hip/hip_runtime.h>
#include <hip/hip_fp16.h>
#include <math.h>

#define F_IN   128
#define HEADS  4
#define HID    32
#define NCLS   8
#define SLOPE  0.2f
#define CAP    96          // padded-CSR slots per node (P(deg>=96) ~ 1e-44)
#define CHSZ   4096        // fill work-stealing chunk size (edges)

typedef _Float16 half8 __attribute__((ext_vector_type(8)));
typedef float    floatx4 __attribute__((ext_vector_type(4)));

// ---------------------------------------------------------------------------
// Prep: zero cur (padded-CSR cursors) + zero tickets + W1 -> Wt (fp16, W1^T).
// blocks [0,ZB): cur; block ZB: tickets (ALL 512 words — R8 bug: only 256
// were zeroed, leaving 0xAA poison in tickets[256..511] -> negative chunk
// ids -> OOB reads -> abort); blocks (ZB, ZB+64]: Wt.
// ---------------------------------------------------------------------------
__global__ void k_zero_prep(int* __restrict__ cur, int* __restrict__ tickets, int N,
                            const float* __restrict__ W1, _Float16* __restrict__ Wt,
                            int ZB) {
    int b = blockIdx.x;
    if (b < ZB) {
        int i = b * 256 + threadIdx.x;
        if (i < N) cur[i] = 0;
    } else if (b == ZB) {
        for (int i = threadIdx.x; i < 512; i += 256) tickets[i] = 0;
    } else {
        int idx = (b - ZB - 1) * 256 + threadIdx.x;        // [0, 16384)
        int c = idx >> 7, k = idx & 127;
        Wt[c * 128 + k] = (_Float16)W1[k * 128 + c];       // coalesced write
    }
}

// ---------------------------------------------------------------------------
// FUSED: XCD-pinned padded-CSR fill (blocks < FBLK)  ∥  MFMA GEMM1+att1.
//
// Fill: partition p owns dst in [p*Npp,(p+1)*Npp). A block reads its physical
// XCD id (HW_REG_XCC_ID, id=20) and consumes work-stealing tickets for its
// own XCD's partition first, then steals from others (completeness holds
// even if the register read is garbage). All atomics/writes to partition p's
// cur/csr slices then come from one XCD -> lines stay in that XCD's L2.
// One pass produces both degrees (cur) and edge lists (csr[d*CAP+pos]).
//
// GEMM: one wave per 16 rows x 128 cols, K=128, v_mfma_f32_16x16x32_f16.
//   A: lane(q=lane>>4, t=lane&15) holds x[r0+t][kc*32+8q..+8] (fp32->fp16)
//   B: lane holds Wt[ct*16+t][kc*32+8q..+8]   (Wt = W1^T)
//   C: lane holds C[q*4+g][ct*16+t]; att1 dots reduced from fp32 acc.
// ---------------------------------------------------------------------------
__global__ void k_fill_gemm(const int* __restrict__ ei, int* __restrict__ cur,
                            int* __restrict__ csr, int* __restrict__ tickets,
                            int E, int N, int FBLK, int NCH,
                            const float* __restrict__ x, const _Float16* __restrict__ Wt,
                            const float* __restrict__ as1, const float* __restrict__ ad1,
                            _Float16* __restrict__ xwh, float* __restrict__ asrc,
                            float* __restrict__ adst) {
    __shared__ int sChunk;
    if ((int)blockIdx.x < FBLK) {
        // ---------------- XCD-pinned padded-CSR fill ----------------
        // simm16 = width-1(31)<<11 | offset(0)<<6 | id(20)  -> HW_REG_XCC_ID
        unsigned xcc = __builtin_amdgcn_s_getreg((31 << 11) | 20);
        int myp = (int)(xcc & 7);
        int ET = E + N;
        int Npp = (N + 7) >> 3;
        int probe = ei[2 * (threadIdx.x & 63) + 1];
        bool is64 = (__ballot(probe != 0) == 0ULL);
        for (int k = 0; k < 8; k++) {
            int p  = (myp + k) & 7;
            int lo = p * Npp;
            int hi = lo + Npp; if (hi > N) hi = N;
            while (true) {
                if (threadIdx.x == 0) sChunk = atomicAdd(&tickets[p * 64], 1);
                __syncthreads();
                int chunk = sChunk;
                __syncthreads();
                if ((unsigned)chunk >= (unsigned)NCH) break;   // unsigned: garbage-safe
                int base = chunk * CHSZ;
                int lim  = base + CHSZ; if (lim > ET) lim = ET;
                for (int i = base + threadIdx.x; i < lim; i += 256) {
                    int d = (i < E) ? (is64 ? ei[2 * E + 2 * i] : ei[E + i]) : (i - E);
                    if (d < lo || d >= hi) continue;
                    int s = (i < E) ? (is64 ? ei[2 * i] : ei[i]) : d;
                    int pos = atomicAdd(&cur[d], 1);
                    if (pos < CAP) csr[d * CAP + pos] = s;
                }
            }
        }
        return;
    }
    // ---------------- MFMA GEMM1 + att1 ----------------
    int gb   = blockIdx.x - FBLK;
    int wv   = threadIdx.x >> 6;
    int lane = threadIdx.x & 63;
    int r0   = gb * 64 + wv * 16;
    if (r0 >= N) return;
    int q = lane >> 4, t = lane & 15;
    int row = r0 + t;
    bool rok = row < N;

    half8 afr[4];
    #pragma unroll
    for (int kc = 0; kc < 4; kc++) {
        float4 u0 = make_float4(0.f, 0.f, 0.f, 0.f), u1 = u0;
        if (rok) {
            const float* xr = x + (size_t)row * 128 + kc * 32 + q * 8;
            u0 = *(const float4*)xr;
            u1 = *(const float4*)(xr + 4);
        }
        afr[kc][0] = (_Float16)u0.x; afr[kc][1] = (_Float16)u0.y;
        afr[kc][2] = (_Float16)u0.z; afr[kc][3] = (_Float16)u0.w;
        afr[kc][4] = (_Float16)u1.x; afr[kc][5] = (_Float16)u1.y;
        afr[kc][6] = (_Float16)u1.z; afr[kc][7] = (_Float16)u1.w;
    }

    float ps[4], pd[4];
    #pragma unroll
    for (int ct = 0; ct < 8; ct++) {
        floatx4 acc = {0.f, 0.f, 0.f, 0.f};
        #pragma unroll
        for (int kc = 0; kc < 4; kc++) {
            half8 b = *(const half8*)(Wt + (ct * 16 + t) * 128 + kc * 32 + q * 8);
            acc = __builtin_amdgcn_mfma_f32_16x16x32_f16(afr[kc], b, acc, 0, 0, 0);
        }
        int col = ct * 16 + t;
        float sa = as1[col], da = ad1[col];
        if ((ct & 1) == 0) {
            #pragma unroll
            for (int g = 0; g < 4; g++) { ps[g] = 0.f; pd[g] = 0.f; }
        }
        #pragma unroll
        for (int g = 0; g < 4; g++) {
            int r = r0 + q * 4 + g;
            if (r < N) xwh[(size_t)r * 128 + col] = (_Float16)acc[g];
            ps[g] += acc[g] * sa;
            pd[g] += acc[g] * da;
        }
        if (ct & 1) {
            int h = ct >> 1;
            #pragma unroll
            for (int g = 0; g < 4; g++) {
                float a = ps[g], d = pd[g];
                a += __shfl_xor(a, 1); d += __shfl_xor(d, 1);
                a += __shfl_xor(a, 2); d += __shfl_xor(d, 2);
                a += __shfl_xor(a, 4); d += __shfl_xor(d, 4);
                a += __shfl_xor(a, 8); d += __shfl_xor(d, 8);
                int r = r0 + q * 4 + g;
                if (t == 0 && r < N) { asrc[r * 4 + h] = a; adst[r * 4 + h] = d; }
            }
        }
    }
}

// ---------------------------------------------------------------------------
// Layer-1 aggregation + fused GEMM2/att2 epilogue. One wave per dst node.
// Padded CSR: list = csr[node*CAP .. node*CAP+deg). Two-phase softmax.
// Epilogue: W2 in registers, value-splitting butterfly.
// ---------------------------------------------------------------------------
__global__ void k_agg1(const _Float16* __restrict__ xwh, const float* __restrict__ asrc,
                       const float* __restrict__ adst, const int* __restrict__ cur,
                       const int* __restrict__ csr, const float* __restrict__ b1,
                       const float* __restrict__ W2, const float* __restrict__ as2,
                       const float* __restrict__ ad2, float* __restrict__ xw2,
                       float* __restrict__ asrc2, float* __restrict__ adst2, int N) {
    int node = (blockIdx.x * blockDim.x + threadIdx.x) >> 6;
    int lane = threadIdx.x & 63;
    if (node >= N) return;
    int h = lane >> 4;
    int t = lane & 15;
    int ch = h * 32 + 2 * t;

    const float4* w2p = (const float4*)(W2 + ch * 8);
    float4 wa0 = w2p[0], wa1 = w2p[1];
    float4 wb0 = w2p[2], wb1 = w2p[3];
    float a_s = as2[lane & 7];
    float a_d = ad2[lane & 7];

    float adst_h = adst[node * 4 + h];
    int beg = node * CAP;
    int deg = cur[node]; if (deg > CAP) deg = CAP;
    int end = beg + deg;

    // ---- Phase A: per-head max, edge-parallel across 16 lanes ----
    float mx = -3.0e38f;
    for (int j = beg + t; j < end; j += 16) {
        float e = asrc[csr[j] * 4 + h] + adst_h;
        e = (e > 0.f) ? e : SLOPE * e;
        mx = fmaxf(mx, e);
    }
    mx = fmaxf(mx, __shfl_xor(mx, 1));
    mx = fmaxf(mx, __shfl_xor(mx, 2));
    mx = fmaxf(mx, __shfl_xor(mx, 4));
    mx = fmaxf(mx, __shfl_xor(mx, 8));

    // ---- Phase B: accumulate with known max (no rescale chain) ----
    float s = 0.f, a0 = 0.f, a1 = 0.f;
    int j = beg;
    for (; j + 4 <= end; j += 4) {
        int s0 = csr[j], s1 = csr[j + 1], s2 = csr[j + 2], s3 = csr[j + 3];
        float e0 = asrc[s0 * 4 + h] + adst_h;
        float e1 = asrc[s1 * 4 + h] + adst_h;
        float e2 = asrc[s2 * 4 + h] + adst_h;
        float e3 = asrc[s3 * 4 + h] + adst_h;
        float2 f0 = __half22float2(*(const __half2*)(xwh + (size_t)s0 * 128 + ch));
        float2 f1 = __half22float2(*(const __half2*)(xwh + (size_t)s1 * 128 + ch));
        float2 f2 = __half22float2(*(const __half2*)(xwh + (size_t)s2 * 128 + ch));
        float2 f3 = __half22float2(*(const __half2*)(xwh + (size_t)s3 * 128 + ch));
        e0 = (e0 > 0.f) ? e0 : SLOPE * e0;
        e1 = (e1 > 0.f) ? e1 : SLOPE * e1;
        e2 = (e2 > 0.f) ? e2 : SLOPE * e2;
        e3 = (e3 > 0.f) ? e3 : SLOPE * e3;
        float p0 = __expf(e0 - mx);
        float p1 = __expf(e1 - mx);
        float p2 = __expf(e2 - mx);
        float p3 = __expf(e3 - mx);
        s  += p0 + p1 + p2 + p3;
        a0 += p0 * f0.x + p1 * f1.x + p2 * f2.x + p3 * f3.x;
        a1 += p0 * f0.y + p1 * f1.y + p2 * f2.y + p3 * f3.y;
    }
    for (; j < end; j++) {
        int s0 = csr[j];
        float e0 = asrc[s0 * 4 + h] + adst_h;
        float2 f0 = __half22float2(*(const __half2*)(xwh + (size_t)s0 * 128 + ch));
        e0 = (e0 > 0.f) ? e0 : SLOPE * e0;
        float p0 = __expf(e0 - mx);
        s  += p0;
        a0 += p0 * f0.x;
        a1 += p0 * f0.y;
    }
    float inv = 1.f / s;
    float o0 = fmaxf(a0 * inv + b1[ch],     0.f);   // relu(h)
    float o1 = fmaxf(a1 * inv + b1[ch + 1], 0.f);

    // ---- fused GEMM2: per-lane partials, value-splitting butterfly ----
    float p[8];
    p[0] = o0 * wa0.x + o1 * wb0.x;  p[1] = o0 * wa0.y + o1 * wb0.y;
    p[2] = o0 * wa0.z + o1 * wb0.z;  p[3] = o0 * wa0.w + o1 * wb0.w;
    p[4] = o0 * wa1.x + o1 * wb1.x;  p[5] = o0 * wa1.y + o1 * wb1.y;
    p[6] = o0 * wa1.z + o1 * wb1.z;  p[7] = o0 * wa1.w + o1 * wb1.w;
    float qq[4];
    #pragma unroll
    for (int b = 0; b < 4; b++) {
        float keepv = (lane & 1) ? p[2 * b + 1] : p[2 * b];
        float sendv = (lane & 1) ? p[2 * b]     : p[2 * b + 1];
        qq[b] = keepv + __shfl_xor(sendv, 1);
    }
    float r2[2];
    #pragma unroll
    for (int b = 0; b < 2; b++) {
        float keepv = (lane & 2) ? qq[2 * b + 1] : qq[2 * b];
        float sendv = (lane & 2) ? qq[2 * b]     : qq[2 * b + 1];
        r2[b] = keepv + __shfl_xor(sendv, 2);
    }
    {
        float keepv = (lane & 4) ? r2[1] : r2[0];
        float sendv = (lane & 4) ? r2[0] : r2[1];
        r2[0] = keepv + __shfl_xor(sendv, 4);
    }
    float f = r2[0];
    f += __shfl_xor(f, 8);
    f += __shfl_xor(f, 16);
    f += __shfl_xor(f, 32);
    if (lane < 8) xw2[node * 8 + lane] = f;
    float vs = f * a_s;
    float vd = f * a_d;
    vs += __shfl_xor(vs, 1); vs += __shfl_xor(vs, 2); vs += __shfl_xor(vs, 4);
    vd += __shfl_xor(vd, 1); vd += __shfl_xor(vd, 2); vd += __shfl_xor(vd, 4);
    if (lane == 0) { asrc2[node] = vs; adst2[node] = vd; }
}

// ---------------------------------------------------------------------------
// Layer-2 aggregation + log_softmax. One wave per node (padded CSR):
// lane = slot(0..7)*8 + class(0..7); slot-parallel online softmax, merged
// by the associative online-softmax merge (masks 8/16/32).
// ---------------------------------------------------------------------------
__global__ void k_agg2(const float* __restrict__ xw2, const float* __restrict__ asrc2,
                       const float* __restrict__ adst2, const int* __restrict__ cur,
                       const int* __restrict__ csr, const float* __restrict__ b2,
                       float* __restrict__ out, int N) {
    int node = (blockIdx.x * blockDim.x + threadIdx.x) >> 6;
    int lane = threadIdx.x & 63;
    if (node >= N) return;
    int slot = lane >> 3;
    int c    = lane & 7;
    float adst = adst2[node];
    int beg = node * CAP;
    int deg = cur[node]; if (deg > CAP) deg = CAP;
    int end = beg + deg;
    float m = -3.0e38f, s = 0.f, acc = 0.f;
    for (int j = beg + slot; j < end; j += 8) {
        int s0 = csr[j];
        float e0 = asrc2[s0] + adst;
        float v0 = xw2[s0 * 8 + c];
        e0 = (e0 > 0.f) ? e0 : SLOPE * e0;
        float mn = fmaxf(m, e0);
        float sc = __expf(m - mn);
        float p0 = __expf(e0 - mn);
        s   = s   * sc + p0;
        acc = acc * sc + p0 * v0;
        m = mn;
    }
    #pragma unroll
    for (int mk = 8; mk < 64; mk <<= 1) {
        float m2 = __shfl_xor(m, mk);
        float s2 = __shfl_xor(s, mk);
        float a2 = __shfl_xor(acc, mk);
        float mn = fmaxf(m, m2);
        float c1 = __expf(m - mn);
        float c2 = __expf(m2 - mn);
        s   = s * c1 + s2 * c2;
        acc = acc * c1 + a2 * c2;
        m = mn;
    }
    float o = acc / s + b2[c];
    float mxv = o;
    mxv = fmaxf(mxv, __shfl_xor(mxv, 1));
    mxv = fmaxf(mxv, __shfl_xor(mxv, 2));
    mxv = fmaxf(mxv, __shfl_xor(mxv, 4));
    float ex = __expf(o - mxv);
    float se = ex;
    se += __shfl_xor(se, 1); se += __shfl_xor(se, 2); se += __shfl_xor(se, 4);
    if (slot == 0) out[node * 8 + c] = o - mxv - __logf(se);
}

// ---------------------------------------------------------------------------
extern "C" void kernel_launch(void* const* d_in, const int* in_sizes, int n_in,
                              void* d_out, int out_size, void* d_ws, size_t ws_size,
                              hipStream_t stream) {
    const float* x   = (const float*)d_in[0];
    const int*   ei  = (const int*)d_in[1];
    const float* W1  = (const float*)d_in[2];
    const float* as1 = (const float*)d_in[3];
    const float* ad1 = (const float*)d_in[4];
    const float* b1  = (const float*)d_in[5];
    const float* W2  = (const float*)d_in[6];
    const float* as2 = (const float*)d_in[7];
    const float* ad2 = (const float*)d_in[8];
    const float* b2  = (const float*)d_in[9];
    float* out = (float*)d_out;

    int N = in_sizes[0] / F_IN;
    int E = in_sizes[1] / 2;
    int ET = E + N;                       // edges incl. self loops
    int ZB = (N + 255) / 256;             // cur-zero blocks
    int GB = (N + 63) / 64;               // gemm blocks (64 rows each)
    int FBLK = 512;                       // fill blocks
    int NCH  = (ET + CHSZ - 1) / CHSZ;    // work-stealing chunks per partition

    // workspace carve
    char* p = (char*)d_ws;
    auto carve = [&](size_t bytes) { char* q = p; p += (bytes + 255) & ~(size_t)255; return (void*)q; };
    _Float16* xw1h = (_Float16*)carve((size_t)N * 128 * 2);
    _Float16* Wt   = (_Float16*)carve(128 * 128 * 2);
    float* asrc1 = (float*)carve((size_t)N * 4 * 4);
    float* adst1 = (float*)carve((size_t)N * 4 * 4);
    float* xw2   = (float*)carve((size_t)N * 8 * 4);
    float* asrc2 = (float*)carve((size_t)N * 4);
    float* adst2 = (float*)carve((size_t)N * 4);
    int*   cur   = (int*)carve((size_t)N * 4);
    int*   tick  = (int*)carve(512 * 4);
    int*   csr   = (int*)carve((size_t)N * CAP * 4);

    // --- prep: cur/tickets zero ∥ W1->Wt fp16 transpose ---
    k_zero_prep<<<ZB + 1 + 64, 256, 0, stream>>>(cur, tick, N, W1, Wt, ZB);

    // --- XCD-pinned padded-CSR fill ∥ MFMA GEMM1+att1 ---
    k_fill_gemm<<<FBLK + GB, 256, 0, stream>>>(ei, cur, csr, tick, E, N, FBLK, NCH,
                                               x, Wt, as1, ad1, xw1h, asrc1, adst1);

    // --- agg1 + gemm2 + att2 fused ---
    k_agg1<<<(N + 3) / 4, 256, 0, stream>>>(xw1h, asrc1, adst1, cur, csr, b1,
                                            W2, as2, ad2, xw2, asrc2, adst2, N);

    // --- layer 2 aggregation + log_softmax (1 wave / node) ---
    k_agg2<<<(N + 3) / 4, 256, 0, stream>>>(xw2, asrc2, adst2, cur, csr, b2, out, N);
}